// Round 6
// baseline (368.282 us; speedup 1.0000x reference)
//
#include <hip/hip_runtime.h>
#include <math.h>

#define BB 2
#define TT 2048
#define DD 2048
#define HH 16
#define KVHN 4
#define HDIM 128
#define NKV 3072   // packed q|k|v row width

typedef unsigned short u16;
typedef unsigned int u32;
typedef __bf16 bf16x8 __attribute__((ext_vector_type(8)));
typedef float  f32x4  __attribute__((ext_vector_type(4)));

#define AS1 __attribute__((address_space(1)))
#define AS3 __attribute__((address_space(3)))

__device__ __forceinline__ void dma16(const u16* g, u16* l) {
  __builtin_amdgcn_global_load_lds((const AS1 u32*)g, (AS3 u32*)l, 16, 0, 0);
}

__device__ __forceinline__ u16 f2bf(float f) {
  u32 u = __float_as_uint(f);
  u32 r = (u + 0x7FFFu + ((u >> 16) & 1u)) >> 16;
  return (u16)r;
}
__device__ __forceinline__ float bf2f(u32 h) { return __uint_as_float(h << 16); }

__device__ __forceinline__ u32 pack2(float a, float b) {
  union { __bf16 h[2]; u32 u; } cv;
  cv.h[0] = (__bf16)a; cv.h[1] = (__bf16)b;
  return cv.u;
}

// ---------------- fused prep: cast x + transpose/cast all weights ----------
__device__ __forceinline__ void tc_body(const float* __restrict__ W,
                                        u16* __restrict__ WT,
                                        int N, int n0, int k0, int tid,
                                        float (*tile)[33]) {
  const int r = tid >> 3;
  const int c4 = (tid & 7) * 4;
  float4 v = *(const float4*)(W + (size_t)(k0 + r) * N + n0 + c4);
  tile[r][c4 + 0] = v.x; tile[r][c4 + 1] = v.y;
  tile[r][c4 + 2] = v.z; tile[r][c4 + 3] = v.w;
  __syncthreads();
  ushort4 o;
  o.x = f2bf(tile[c4 + 0][r]); o.y = f2bf(tile[c4 + 1][r]);
  o.z = f2bf(tile[c4 + 2][r]); o.w = f2bf(tile[c4 + 3][r]);
  *(ushort4*)(WT + (size_t)(n0 + r) * DD + k0 + c4) = o;
}

__global__ __launch_bounds__(256) void prep(const float* __restrict__ x,
                                            const float* __restrict__ Wq,
                                            const float* __restrict__ Wk,
                                            const float* __restrict__ Wv,
                                            const float* __restrict__ Wo,
                                            u16* __restrict__ xb,
                                            u16* __restrict__ WqkvT,
                                            u16* __restrict__ WoT) {
  __shared__ float tile[32][33];
  const int bid = blockIdx.x;
  const int tid = threadIdx.x;
  if (bid < 8192) {
    size_t i4 = (size_t)bid * 256 + tid;
    float4 v = *(const float4*)(x + i4 * 4);
    ushort4 o;
    o.x = f2bf(v.x); o.y = f2bf(v.y); o.z = f2bf(v.z); o.w = f2bf(v.w);
    *(ushort4*)(xb + i4 * 4) = o;
  } else if (bid < 12288) {
    int idx = bid - 8192;
    tc_body(Wq, WqkvT, DD, (idx & 63) * 32, (idx >> 6) * 32, tid, tile);
  } else if (bid < 13312) {
    int idx = bid - 12288;
    tc_body(Wk, WqkvT + (size_t)2048 * DD, 512, (idx & 15) * 32, (idx >> 4) * 32, tid, tile);
  } else if (bid < 14336) {
    int idx = bid - 13312;
    tc_body(Wv, WqkvT + (size_t)2560 * DD, 512, (idx & 15) * 32, (idx >> 4) * 32, tid, tile);
  } else {
    int idx = bid - 14336;
    tc_body(Wo, WoT, DD, (idx & 63) * 32, (idx >> 6) * 32, tid, tile);
  }
}

// ---------------- QKV GEMM with fused RoPE + V-transpose epilogue ----------
// C = xb @ WqkvT^T ; n-tile 0..15 = q heads (rope+scale), 16..19 = k heads
// (rope), 20..23 = v heads (transposed store to Vt). 128x128 tile, BK=32.
__global__ __launch_bounds__(256) void gemm_qkv(const u16* __restrict__ A,
                                                const u16* __restrict__ BT,
                                                u16* __restrict__ QKV,
                                                u16* __restrict__ Vt) {
  __shared__ u16 smem[128 * 64];       // As = [0,4096), Bs = [4096,8192)
  u16* As = smem;
  u16* Bs = smem + 128 * 32;
  const int t = threadIdx.x;
  const int l = t & 63, w = t >> 6;
  const int lm = l & 15, quad = l >> 4;
  const int wm = w & 1, wn = w >> 1;
  const int tile = blockIdx.x;
  const int m0 = blockIdx.y * 128, n0 = tile * 128;
  const int wu = __builtin_amdgcn_readfirstlane(w);

  f32x4 acc[4][4];
  #pragma unroll
  for (int i = 0; i < 4; ++i)
    #pragma unroll
    for (int j = 0; j < 4; ++j) acc[i][j] = (f32x4){0.f, 0.f, 0.f, 0.f};

  for (int k0 = 0; k0 < DD; k0 += 32) {
    __syncthreads();
    #pragma unroll
    for (int i = 0; i < 2; ++i) {
      int p0 = (wu * 2 + i) * 64;
      int p = p0 + l;
      int row = p >> 2, c = p & 3;
      dma16(A  + (size_t)(m0 + row) * DD + k0 + c * 8, &As[p0 * 8]);
      dma16(BT + (size_t)(n0 + row) * DD + k0 + c * 8, &Bs[p0 * 8]);
    }
    __syncthreads();
    bf16x8 a[4], bq[4];
    #pragma unroll
    for (int i = 0; i < 4; ++i)
      a[i] = *(const bf16x8*)&As[(wm * 64 + i * 16 + lm) * 32 + quad * 8];
    #pragma unroll
    for (int j = 0; j < 4; ++j)
      bq[j] = *(const bf16x8*)&Bs[(wn * 64 + j * 16 + lm) * 32 + quad * 8];
    #pragma unroll
    for (int i = 0; i < 4; ++i)
      #pragma unroll
      for (int j = 0; j < 4; ++j)
        acc[i][j] = __builtin_amdgcn_mfma_f32_16x16x32_bf16(a[i], bq[j], acc[i][j], 0, 0, 0);
  }

  const int b = m0 >> 11;
  const int t0 = m0 & 2047;
  if (tile < 20) {
    // q/k head: fused RoPE. Pair lanes (lm, lm^1) hold cols (2f, 2f+1).
    const float sc = (tile < 16) ? 0.08838834764831845f : 1.0f;
    const int odd = lm & 1;
    #pragma unroll
    for (int j = 0; j < 4; ++j) {
      int cl = wn * 64 + j * 16 + lm;
      int f = cl >> 1;
      float wf = exp2f((float)f * -0.20762050593046898f);  // 10000^(-f/64)
      size_t gc = n0 + (odd ? 64 + f : f);
      #pragma unroll
      for (int i = 0; i < 4; ++i) {
        #pragma unroll
        for (int r = 0; r < 4; ++r) {
          int row = wm * 64 + i * 16 + quad * 4 + r;
          float own = acc[i][j][r];
          float oth = __shfl_xor(own, 1);
          float e = odd ? oth : own;     // even col value (2f)
          float o = odd ? own : oth;     // odd col value (2f+1)
          float ang = (float)(t0 + row) * wf;
          float sn, cs;
          __sincosf(ang, &sn, &cs);
          float res = odd ? (e * sn + o * cs) : (e * cs - o * sn);
          QKV[(size_t)(m0 + row) * NKV + gc] = f2bf(res * sc);
        }
      }
    }
  } else {
    // v head: transposed store -> Vt[(b*4+vh)*128 + d][t], via smem reuse
    const int vh = tile - 20;
    #pragma unroll
    for (int half = 0; half < 2; ++half) {
      __syncthreads();
      if (wm == half) {
        #pragma unroll
        for (int j = 0; j < 4; ++j) {
          int d = wn * 64 + j * 16 + lm;
          #pragma unroll
          for (int i = 0; i < 4; ++i)
            #pragma unroll
            for (int r = 0; r < 4; ++r) {
              int tl = i * 16 + quad * 4 + r;           // 0..63
              int pt = tl ^ ((d & 7) * 8);              // 8-granular swizzle
              smem[d * 64 + pt] = f2bf(acc[i][j][r]);
            }
        }
      }
      __syncthreads();
      #pragma unroll
      for (int it = 0; it < 4; ++it) {
        int p = it * 256 + t;
        int d = p >> 3, c = p & 7;
        int pc = c ^ (d & 7);
        uint4 val = *(const uint4*)&smem[d * 64 + pc * 8];
        *(uint4*)(Vt + ((size_t)((b * KVHN + vh) * HDIM + d)) * TT +
                  t0 + half * 64 + c * 8) = val;
      }
    }
  }
}

// ---------------- m97-style MFMA GEMM: C = A @ BT^T (final Wo) -------------
__global__ __launch_bounds__(256) void gemm2(const u16* __restrict__ A,
                                             const u16* __restrict__ BT,
                                             float* __restrict__ Cv,
                                             int N, int K) {
  __shared__ u16 As[128 * 32];
  __shared__ u16 Bs[128 * 32];
  const int t = threadIdx.x;
  const int l = t & 63, w = t >> 6;
  const int lm = l & 15, quad = l >> 4;
  const int wm = w & 1, wn = w >> 1;
  const int m0 = blockIdx.y * 128, n0 = blockIdx.x * 128;
  const int wu = __builtin_amdgcn_readfirstlane(w);

  f32x4 acc[4][4];
  #pragma unroll
  for (int i = 0; i < 4; ++i)
    #pragma unroll
    for (int j = 0; j < 4; ++j) acc[i][j] = (f32x4){0.f, 0.f, 0.f, 0.f};

  for (int k0 = 0; k0 < K; k0 += 32) {
    __syncthreads();
    #pragma unroll
    for (int i = 0; i < 2; ++i) {
      int p0 = (wu * 2 + i) * 64;
      int p = p0 + l;
      int row = p >> 2, c = p & 3;
      dma16(A  + (size_t)(m0 + row) * K + k0 + c * 8, &As[p0 * 8]);
      dma16(BT + (size_t)(n0 + row) * K + k0 + c * 8, &Bs[p0 * 8]);
    }
    __syncthreads();
    bf16x8 a[4], bq[4];
    #pragma unroll
    for (int i = 0; i < 4; ++i)
      a[i] = *(const bf16x8*)&As[(wm * 64 + i * 16 + lm) * 32 + quad * 8];
    #pragma unroll
    for (int j = 0; j < 4; ++j)
      bq[j] = *(const bf16x8*)&Bs[(wn * 64 + j * 16 + lm) * 32 + quad * 8];
    #pragma unroll
    for (int i = 0; i < 4; ++i)
      #pragma unroll
      for (int j = 0; j < 4; ++j)
        acc[i][j] = __builtin_amdgcn_mfma_f32_16x16x32_bf16(a[i], bq[j], acc[i][j], 0, 0, 0);
  }

  #pragma unroll
  for (int i = 0; i < 4; ++i) {
    #pragma unroll
    for (int r = 0; r < 4; ++r) {
      size_t gr = (size_t)(m0 + wm * 64 + i * 16 + quad * 4 + r);
      #pragma unroll
      for (int j = 0; j < 4; ++j) {
        int gc = n0 + wn * 64 + j * 16 + lm;
        Cv[gr * N + gc] = acc[i][j][r];
      }
    }
  }
}

// ---------------- MFMA flash attention (R4-proven: paired, DMA dbuf) -------
// Block: 256 thr = 4 waves; q-tile pair {px, 31-px} (2x64 rows); KV-tile 64.
__global__ __launch_bounds__(256, 2) void attn2(const u16* __restrict__ QKV,
                                                const u16* __restrict__ Vt,
                                                u16* __restrict__ Ob) {
  __shared__ u16 KsA[64 * 128], KsB[64 * 128];
  __shared__ u16 VsA[128 * 64], VsB[128 * 64];
  __shared__ u16 Pw[4 * 2048];
  const int t = threadIdx.x;
  const int l = t & 63, w = t >> 6;
  const int lm = l & 15, quad = l >> 4;
  const int px = blockIdx.x, h = blockIdx.y, b = blockIdx.z;
  const int kvh = h >> 2;
  const int qlo = px * 64, qhi = (31 - px) * 64;
  const int last = 31 - px;
  const int wu = __builtin_amdgcn_readfirstlane(w);
  u16* pwv = &Pw[w * 2048];
  constexpr float L2E = 1.4426950408889634f;

  // Q fragments (B-operand: rows q=lm, contiguous k)
  bf16x8 qf[2][4];
  {
    size_t r0 = (size_t)(b * TT + qlo + w * 16 + lm) * NKV + h * HDIM;
    size_t r1 = (size_t)(b * TT + qhi + w * 16 + lm) * NKV + h * HDIM;
    #pragma unroll
    for (int ks = 0; ks < 4; ++ks) {
      qf[0][ks] = *(const bf16x8*)(QKV + r0 + ks * 32 + quad * 8);
      qf[1][ks] = *(const bf16x8*)(QKV + r1 + ks * 32 + quad * 8);
    }
  }

  f32x4 o[8][2];
  #pragma unroll
  for (int i = 0; i < 8; ++i)
    #pragma unroll
    for (int n = 0; n < 2; ++n) o[i][n] = (f32x4){0.f, 0.f, 0.f, 0.f};
  float m_[2] = {-1e30f, -1e30f}, l_[2] = {0.f, 0.f};

  auto stageK = [&](int kt, u16* dst) {
    #pragma unroll
    for (int i = 0; i < 4; ++i) {
      int p0 = (wu * 4 + i) * 64;
      int p = p0 + l;
      int row = p >> 4, cp = p & 15, cl = cp ^ (row & 15);
      dma16(QKV + (size_t)(b * TT + kt * 64 + row) * NKV + 2048 + kvh * HDIM + cl * 8,
            dst + p0 * 8);
    }
  };
  auto stageV = [&](int kt, u16* dst) {
    #pragma unroll
    for (int i = 0; i < 4; ++i) {
      int p0 = (wu * 4 + i) * 64;
      int p = p0 + l;
      int d = p >> 3, cp = p & 7, cl = cp ^ (d & 7);
      dma16(Vt + (size_t)((b * KVHN + kvh) * HDIM + d) * TT + kt * 64 + cl * 8,
            dst + p0 * 8);
    }
  };

  auto body = [&](int kt, u16* kcur, u16* vcur, u16* knext, u16* vnext) {
    __syncthreads();                       // cur buffers landed; prev reads done
    const bool pf = kt < last;
    if (pf) stageV(kt + 1, vnext);
    const bool lo = (kt <= px);

    // S^T = K . Q^T
    f32x4 s[4][2];
    #pragma unroll
    for (int mt = 0; mt < 4; ++mt) {
      s[mt][0] = (f32x4){0.f, 0.f, 0.f, 0.f};
      s[mt][1] = (f32x4){0.f, 0.f, 0.f, 0.f};
    }
    #pragma unroll
    for (int ks = 0; ks < 4; ++ks) {
      #pragma unroll
      for (int mt = 0; mt < 4; ++mt) {
        bf16x8 kb = *(const bf16x8*)&kcur[(mt * 16 + lm) * 128 + (((ks * 4 + quad) ^ lm) * 8)];
        if (lo) s[mt][0] = __builtin_amdgcn_mfma_f32_16x16x32_bf16(kb, qf[0][ks], s[mt][0], 0, 0, 0);
        s[mt][1] = __builtin_amdgcn_mfma_f32_16x16x32_bf16(kb, qf[1][ks], s[mt][1], 0, 0, 0);
      }
    }
    if (pf) stageK(kt + 1, knext);

    // causal mask on diagonal tiles
    if (kt == px) {
      #pragma unroll
      for (int mt = 0; mt < 4; ++mt)
        #pragma unroll
        for (int r = 0; r < 4; ++r) {
          int kv = kt * 64 + mt * 16 + quad * 4 + r;
          if (kv > qlo + w * 16 + lm) s[mt][0][r] = -1e30f;
        }
    }
    if (kt == last) {
      #pragma unroll
      for (int mt = 0; mt < 4; ++mt)
        #pragma unroll
        for (int r = 0; r < 4; ++r) {
          int kv = kt * 64 + mt * 16 + quad * 4 + r;
          if (kv > qhi + w * 16 + lm) s[mt][1][r] = -1e30f;
        }
    }

    // online softmax per q-tile (reduce: in-lane 16 + cross-quad shfl x2)
    float al[2] = {1.f, 1.f};
    #pragma unroll
    for (int nt = 0; nt < 2; ++nt) {
      if (nt == 0 && !lo) continue;
      float mx = -1e30f;
      #pragma unroll
      for (int mt = 0; mt < 4; ++mt)
        #pragma unroll
        for (int r = 0; r < 4; ++r) mx = fmaxf(mx, s[mt][nt][r]);
      mx = fmaxf(mx, __shfl_xor(mx, 16));
      mx = fmaxf(mx, __shfl_xor(mx, 32));
      float mn = fmaxf(m_[nt], mx);
      al[nt] = exp2f((m_[nt] - mn) * L2E);
      m_[nt] = mn;
      float sum = 0.f;
      #pragma unroll
      for (int mt = 0; mt < 4; ++mt)
        #pragma unroll
        for (int r = 0; r < 4; ++r) {
          float pv = exp2f((s[mt][nt][r] - mn) * L2E);
          s[mt][nt][r] = pv;
          sum += pv;
        }
      sum += __shfl_xor(sum, 16);
      sum += __shfl_xor(sum, 32);
      l_[nt] = l_[nt] * al[nt] + sum;

      // P -> LDS (b64 swizzled), per-wave region
      #pragma unroll
      for (int mt = 0; mt < 4; ++mt) {
        u32 p01 = pack2(s[mt][nt][0], s[mt][nt][1]);
        u32 p23 = pack2(s[mt][nt][2], s[mt][nt][3]);
        int phys = (mt * 2 + (quad >> 1)) ^ (lm & 7);
        int addr = (nt * 16 + lm) * 64 + phys * 8 + (quad & 1) * 4;
        uint2 uv; uv.x = p01; uv.y = p23;
        *(uint2*)&pwv[addr] = uv;
      }
      // O^T rescale
      if (__any(al[nt] < 1.0f)) {
        #pragma unroll
        for (int mt2 = 0; mt2 < 8; ++mt2)
          #pragma unroll
          for (int r = 0; r < 4; ++r) o[mt2][nt][r] *= al[nt];
      }
    }

    // O^T += V^T . P^T
    #pragma unroll
    for (int ks2 = 0; ks2 < 2; ++ks2) {
      int coff = ((ks2 * 4 + quad) ^ (lm & 7)) * 8;
      bf16x8 pb0, pb1;
      if (lo) pb0 = *(const bf16x8*)&pwv[lm * 64 + coff];
      pb1 = *(const bf16x8*)&pwv[(16 + lm) * 64 + coff];
      #pragma unroll
      for (int mt2 = 0; mt2 < 8; ++mt2) {
        bf16x8 vb = *(const bf16x8*)&vcur[(mt2 * 16 + lm) * 64 + coff];
        if (lo) o[mt2][0] = __builtin_amdgcn_mfma_f32_16x16x32_bf16(vb, pb0, o[mt2][0], 0, 0, 0);
        o[mt2][1] = __builtin_amdgcn_mfma_f32_16x16x32_bf16(vb, pb1, o[mt2][1], 0, 0, 0);
      }
    }
  };

  stageK(0, KsA); stageV(0, VsA);
  for (int kt = 0; kt <= last; ++kt) {
    if ((kt & 1) == 0) body(kt, KsA, VsA, KsB, VsB);
    else               body(kt, KsB, VsB, KsA, VsA);
  }

  // epilogue: O^T -> LDS transpose -> coalesced bf16 stores
  #pragma unroll
  for (int nt = 0; nt < 2; ++nt) {
    float inv = 1.f / l_[nt];
    #pragma unroll
    for (int mt2 = 0; mt2 < 8; ++mt2) {
      u32 a0 = pack2(o[mt2][nt][0] * inv, o[mt2][nt][1] * inv);
      u32 a1 = pack2(o[mt2][nt][2] * inv, o[mt2][nt][3] * inv);
      int phys = (mt2 * 2 + (quad >> 1)) ^ (lm & 7);
      int addr = lm * 128 + phys * 8 + (quad & 1) * 4;
      uint2 uv; uv.x = a0; uv.y = a1;
      *(uint2*)&pwv[addr] = uv;
    }
    int qt0 = nt ? qhi : qlo;
    #pragma unroll
    for (int i = 0; i < 4; ++i) {
      int p = i * 64 + l;
      int row = p >> 4, cl = p & 15;
      int cph = cl ^ (row & 7);
      uint4 val = *(const uint4*)&pwv[row * 128 + cph * 8];
      *(uint4*)(Ob + (size_t)(b * TT + qt0 + w * 16 + row) * DD + h * HDIM + cl * 8) = val;
    }
  }
}

extern "C" void kernel_launch(void* const* d_in, const int* in_sizes, int n_in,
                              void* d_out, int out_size, void* d_ws, size_t ws_size,
                              hipStream_t stream) {
  const float* x  = (const float*)d_in[0];
  const float* Wq = (const float*)d_in[1];
  const float* Wk = (const float*)d_in[2];
  const float* Wv = (const float*)d_in[3];
  const float* Wo = (const float*)d_in[4];
  float* out = (float*)d_out;

  // ws (u16 elems): xb @0 (8M, -> Ob) | WqkvT @8M (6M) | WoT @14.68M (4M)
  // d_out (u16 elems): QKVb @0 (12.58M) | Vt @12.58M (2.1M) -> both dead
  // before the final GEMM overwrites d_out with fp32.
  u16* xb    = (u16*)d_ws;
  u16* WqkvT = xb + 8388608;
  u16* WoT   = xb + 14680064;
  u16* Ob    = xb;                        // alias, live after gemm_qkv
  u16* QKVb  = (u16*)d_out;
  u16* Vt    = QKVb + (size_t)4096 * NKV; // tail of d_out, 4 MB

  dim3 blk(256);
  prep<<<18432, blk, 0, stream>>>(x, Wq, Wk, Wv, Wo, xb, WqkvT, WoT);
  gemm_qkv<<<dim3(NKV / 128, 32), blk, 0, stream>>>(xb, WqkvT, QKVb, Vt);
  attn2<<<dim3(16, HH, BB), blk, 0, stream>>>(QKVb, Vt, Ob);
  gemm2<<<dim3(DD / 128, 32), blk, 0, stream>>>(Ob, WoT, out, DD, DD);
}